// Round 2
// baseline (63.918 us; speedup 1.0000x reference)
//
#include <hip/hip_runtime.h>

// KaolinRenderer: coverage-mask rasterizer.
// Output = repeat(mask[B,H,W], 3) — the reference z-buffer is dead code.
//
// BIT-EXACTNESS IS CRITICAL: mask is binary, threshold 2e-2. Faces with
// w-clamped vertices (|ndc| ~1e8) have catastrophically-cancelling edge
// functions whose sign is rounding-determined. We mirror the numpy reference's
// float32 op order exactly and disable FMA contraction for every value that
// feeds the exact inside-test. Skipping faces once `covered` is true is safe
// (sticky OR); changing per-face exact-test arithmetic is not.
//
// R8: three changes, all targeting ISSUE COUNT + tail (R7 taught us latency
// was already hidden at 2 waves/SIMD; readlane==bpermute in issue cost):
//  (1) Cull data (A,B,C,err per edge) hoisted to face_pack — was recomputed
//      per-wave (1024x per face). Raster cull is now a midpoint-spread test
//      base±spread vs ±err: mathematically equal to the validated corner-
//      select max/min of the linear model; FMA allowed in the cull ONLY
//      (conservative test; CULL_EPS=2^-16 has ~2^8 slack over f32 rounding,
//      re-association noise is ~err/40). ~100 -> ~40 wave-inst per group.
//  (2) Survivor eval uses stored A=dx, B=-dy: e = A*(py-ya) + B*(px-ax) is
//      IEEE-bit-identical to reference dx*(py-ya) - dy*(px-ax) since
//      (-a)*b == -(a*b) and x+(-w) == x-w exactly. 12 readlane broadcasts
//      (wave-uniform k -> scalar file). Per-survivor __all(covered) check
//      REMOVED (pure overhead for the uncovered waves that set the tail;
//      group-level check retained). min3/max3 via nested fminf/fmaxf.
//  (3) 64-thread blocks (2048 blocks, one 8x8 rect per wave): 8 schedulable
//      units/CU instead of 2 -> hardware smooths the silhouette-tile tail.
// R6/R7: register cull + ballot compaction; no memory ops in survivor loop;
// readlane broadcast (k from __ballot is wave-uniform).

#pragma clang fp contract(off)

#define HW      256
#define BATCH   2
#define VCOUNT  4096
#define FCOUNT  4096
#define CULL_EPS 1.52587890625e-05f   // 2^-16

__global__ __launch_bounds__(256)
void face_pack_kernel(const float* __restrict__ verts,
                      const int* __restrict__ faces,
                      const float* __restrict__ R,
                      const float* __restrict__ T,
                      float4* __restrict__ fxy4,   // [B*F] (x0,y0,x1,y1)
                      float2* __restrict__ fxy2,   // [B*F] (x2,y2)
                      float4* __restrict__ ed0,    // [B*F] (A,B,C,err) edge0
                      float4* __restrict__ ed1,    // [B*F] edge1
                      float4* __restrict__ ed2)    // [B*F] edge2
{
#pragma clang fp contract(off)
    int gid = blockIdx.x * blockDim.x + threadIdx.x;
    if (gid >= BATCH * FCOUNT) return;
    int b = gid / FCOUNT;

    const float fproj = 1.7320508075688772f;   // 1/tan(30deg), f64->f32 like numpy

    const float* Rb = R + b * 9;
    const float* Tb = T + b * 3;

    // t_i = -((Rt[i][0]*T0 + Rt[i][1]*T1) + Rt[i][2]*T2), Rt[i][j] = R[j][i]
    float t0 = -((Rb[0*3+0]*Tb[0] + Rb[1*3+0]*Tb[1]) + Rb[2*3+0]*Tb[2]);
    float t1 = -((Rb[0*3+1]*Tb[0] + Rb[1*3+1]*Tb[1]) + Rb[2*3+1]*Tb[2]);
    float t2 = -((Rb[0*3+2]*Tb[0] + Rb[1*3+2]*Tb[1]) + Rb[2*3+2]*Tb[2]);

    // VP rows 0 (x), 1 (y), 3 (w) only.
    float VP00 = fproj * Rb[0*3+0], VP01 = fproj * Rb[1*3+0],
          VP02 = fproj * Rb[2*3+0], VP03 = fproj * t0;
    float VP10 = fproj * Rb[0*3+1], VP11 = fproj * Rb[1*3+1],
          VP12 = fproj * Rb[2*3+1], VP13 = fproj * t1;
    float VP30 = -Rb[0*3+2], VP31 = -Rb[1*3+2],
          VP32 = -Rb[2*3+2], VP33 = -t2;

    const int* fp = faces + (size_t)gid * 3;
    float xs[3], ys[3];
#pragma unroll
    for (int j = 0; j < 3; ++j) {
        const float* vv = verts + ((size_t)b * VCOUNT + fp[j]) * 3;
        float vx = vv[0], vy = vv[1], vz = vv[2];
        // Identical op sequence to the reference einsum (sequential adds),
        // contract off => bit-identical NDC for every reference to a vertex.
        float cx = ((vx*VP00 + vy*VP01) + vz*VP02) + VP03;
        float cy = ((vx*VP10 + vy*VP11) + vz*VP12) + VP13;
        float cw = ((vx*VP30 + vy*VP31) + vz*VP32) + VP33;
        float w = fmaxf(cw, 1e-8f);
        xs[j] = cx / w;
        ys[j] = cy / w;
    }

    fxy4[gid] = make_float4(xs[0], ys[0], xs[1], ys[1]);
    fxy2[gid] = make_float2(xs[2], ys[2]);

    // Diffs: same f32 ops as the reference's (x1-x0) etc.
    float d01x = xs[1] - xs[0], d01y = ys[1] - ys[0];
    float d12x = xs[2] - xs[1], d12y = ys[2] - ys[1];
    float d20x = xs[0] - xs[2], d20y = ys[0] - ys[2];

    // Per-edge linear model of the reference edge function:
    //   e ~= A*py + B*px + C,  A = dx, B = -dy, C = dy*xa - dx*ya
    // err bounds |model - reference_e| over [-1,1]^2 incl. reference rounding
    // (R4-validated formula, unchanged; contract off here keeps C/err
    // bit-identical to the previously validated in-raster computation).
    float C0 = d01y * xs[0] - d01x * ys[0];
    float C1 = d12y * xs[1] - d12x * ys[1];
    float C2 = d20y * xs[2] - d20x * ys[2];
    float e0r = CULL_EPS * (fabsf(d01x) * (1.0f + fabsf(ys[0]))
                          + fabsf(d01y) * (1.0f + fabsf(xs[0])));
    float e1r = CULL_EPS * (fabsf(d12x) * (1.0f + fabsf(ys[1]))
                          + fabsf(d12y) * (1.0f + fabsf(xs[1])));
    float e2r = CULL_EPS * (fabsf(d20x) * (1.0f + fabsf(ys[2]))
                          + fabsf(d20y) * (1.0f + fabsf(xs[2])));

    ed0[gid] = make_float4(d01x, -d01y, C0, e0r);
    ed1[gid] = make_float4(d12x, -d12y, C1, e1r);
    ed2[gid] = make_float4(d20x, -d20y, C2, e2r);
}

// Wave-uniform broadcast through the scalar file (v_readlane_b32).
__device__ __forceinline__ float bcast_lane(float v, int k) {
    return __int_as_float(__builtin_amdgcn_readlane(__float_as_int(v), k));
}

__global__ __launch_bounds__(64)
void raster_kernel(const float4* __restrict__ ed0,
                   const float4* __restrict__ ed1,
                   const float4* __restrict__ ed2,
                   const float4* __restrict__ fxy4,
                   const float2* __restrict__ fxy2,
                   float* __restrict__ out)
{
#pragma clang fp contract(off)
    int b    = blockIdx.y;
    int tile = blockIdx.x;                 // 32x32 tiles of 8x8 over 256x256
    int qx = (tile & 31) << 3;
    int qy = (tile >> 5) << 3;
    int lane = threadIdx.x;                // one wave per block
    int px_i = qx + (lane & 7);
    int py_i = qy + (lane >> 3);

    // Same formula as reference: ((i + 0.5)/W)*2 - 1
    float px = (((float)px_i + 0.5f) / 256.0f) * 2.0f - 1.0f;
    float py = (((float)py_i + 0.5f) / 256.0f) * 2.0f - 1.0f;

    // This wave's 8x8 rect (pixel formula is monotone in index).
    float pxlo = (((float)qx       + 0.5f) / 256.0f) * 2.0f - 1.0f;
    float pxhi = (((float)(qx + 7) + 0.5f) / 256.0f) * 2.0f - 1.0f;
    float pylo = (((float)qy       + 0.5f) / 256.0f) * 2.0f - 1.0f;
    float pyhi = (((float)(qy + 7) + 0.5f) / 256.0f) * 2.0f - 1.0f;
    // Midpoint/half-extent form: for linear f = A*py+B*px+C,
    // max/min over rect = base +/- (|A|*yr + |B|*xr). Cull-only arithmetic.
    float xm = 0.5f * (pxlo + pxhi), xr = 0.5f * (pxhi - pxlo);
    float ym = 0.5f * (pylo + pyhi), yr = 0.5f * (pyhi - pylo);

    const float4* e0p = ed0  + (size_t)b * FCOUNT;
    const float4* e1p = ed1  + (size_t)b * FCOUNT;
    const float4* e2p = ed2  + (size_t)b * FCOUNT;
    const float4* f4  = fxy4 + (size_t)b * FCOUNT;
    const float2* f2  = fxy2 + (size_t)b * FCOUNT;

    bool covered = false;

    for (int g = 0; g < FCOUNT; g += 64) {
        if (__all((int)covered)) break;

        int idx = g + lane;
        float4 E0 = e0p[idx];
        float4 E1 = e1p[idx];
        float4 E2 = e2p[idx];
        float4 q0 = f4[idx];
        float2 q1 = f2[idx];

        // Conservative cull. Skippable iff some edge certifies e<0 over the
        // whole rect AND some edge certifies e>0 (kills both sign branches of
        // `inside`). FMA allowed here: it only tightens the cull's own
        // rounding, and err has ~2^8 slack over f32 eps by construction.
        bool killneg = false, killpos = false;
        {
#pragma clang fp contract(fast)
            float b0 = E0.x * ym + E0.y * xm + E0.z;
            float s0 = fabsf(E0.x) * yr + fabsf(E0.y) * xr;
            killneg = killneg || (b0 + s0 < -E0.w);
            killpos = killpos || (b0 - s0 >  E0.w);
            float b1 = E1.x * ym + E1.y * xm + E1.z;
            float s1 = fabsf(E1.x) * yr + fabsf(E1.y) * xr;
            killneg = killneg || (b1 + s1 < -E1.w);
            killpos = killpos || (b1 - s1 >  E1.w);
            float b2 = E2.x * ym + E2.y * xm + E2.z;
            float s2 = fabsf(E2.x) * yr + fabsf(E2.y) * xr;
            killneg = killneg || (b2 + s2 < -E2.w);
            killpos = killpos || (b2 - s2 >  E2.w);
        }
        bool skip = killneg && killpos;

        // Survivor loop: broadcast lane-k values via v_readlane (k is
        // wave-uniform). No memory ops, no per-survivor ballot check.
        unsigned long long m = __ballot((int)!skip);
        while (m) {
            int k = __ffsll((long long)m) - 1;
            m &= m - 1;
            float A0 = bcast_lane(E0.x, k), B0 = bcast_lane(E0.y, k);
            float A1 = bcast_lane(E1.x, k), B1 = bcast_lane(E1.y, k);
            float A2 = bcast_lane(E2.x, k), B2 = bcast_lane(E2.y, k);
            float ax0 = bcast_lane(q0.x, k), ay0 = bcast_lane(q0.y, k);
            float ax1 = bcast_lane(q0.z, k), ay1 = bcast_lane(q0.w, k);
            float ax2 = bcast_lane(q1.x, k), ay2 = bcast_lane(q1.y, k);
            // e = A*(py-ya) + B*(px-xa), A=dx, B=-dy: bit-identical to the
            // reference dx*(py-ya) - dy*(px-xa) since (-a)*b == -(a*b) and
            // x+(-w) == x-w in IEEE f32. Contract off => no FMA.
            float e0 = A0 * (py - ay0) + B0 * (px - ax0);
            float e1 = A1 * (py - ay1) + B1 * (px - ax1);
            float e2 = A2 * (py - ay2) + B2 * (px - ax2);
            float mn = fminf(fminf(e0, e1), e2);
            float mx = fmaxf(fmaxf(e0, e1), e2);
            covered = covered || (mn >= 0.0f) || (mx <= 0.0f);
        }
    }

    float val = covered ? 1.0f : 0.0f;
    size_t o = ((size_t)(b * HW + py_i) * HW + px_i) * 3;
    out[o + 0] = val;
    out[o + 1] = val;
    out[o + 2] = val;
}

extern "C" void kernel_launch(void* const* d_in, const int* in_sizes, int n_in,
                              void* d_out, int out_size, void* d_ws, size_t ws_size,
                              hipStream_t stream) {
    const float* verts = (const float*)d_in[0];   // [2,4096,3] f32
    const int*   faces = (const int*)d_in[1];     // [2,4096,3] i32
    const float* R     = (const float*)d_in[2];   // [2,3,3]    f32
    const float* T     = (const float*)d_in[3];   // [2,3]      f32
    float*       out   = (float*)d_out;           // [2,256,256,3] f32

    float4* fxy4 = (float4*)d_ws;                        // 128 KiB
    float2* fxy2 = (float2*)(fxy4 + BATCH * FCOUNT);     // 64 KiB
    float4* ed0  = (float4*)(fxy2 + BATCH * FCOUNT);     // 128 KiB
    float4* ed1  = ed0 + BATCH * FCOUNT;                 // 128 KiB
    float4* ed2  = ed1 + BATCH * FCOUNT;                 // 128 KiB

    int nf = BATCH * FCOUNT;
    face_pack_kernel<<<(nf + 255) / 256, 256, 0, stream>>>(verts, faces, R, T,
                                                           fxy4, fxy2,
                                                           ed0, ed1, ed2);

    dim3 grid(32 * 32, BATCH);
    raster_kernel<<<grid, 64, 0, stream>>>(ed0, ed1, ed2, fxy4, fxy2, out);
}